// Round 1
// baseline (275.394 us; speedup 1.0000x reference)
//
#include <hip/hip_runtime.h>

// Problem constants (fixed by the reference)
#define TT    8192          // tokens
#define TOPK  8
#define HH    2048          // hidden
#define EE    64            // experts
#define NFLAT (TT * TOPK)   // 65536 flat (token, slot) pairs
#define NBLK  (NFLAT / 256) // 256 chunks of 256 slots

// ---------------------------------------------------------------------------
// Kernel 1: per-chunk expert histogram + stable in-chunk rank per slot.
// rank[i] = number of j < i within the chunk with the same expert.
// Deterministic (no cross-thread ordering dependence in the rank loop).
// ---------------------------------------------------------------------------
__global__ void k_hist_rank(const int* __restrict__ expi,
                            int* __restrict__ blockHist,
                            int* __restrict__ rank) {
    __shared__ int sh_e[256];
    __shared__ int sh_hist[EE];
    const int tid = threadIdx.x;
    const int gid = blockIdx.x * 256 + tid;
    if (tid < EE) sh_hist[tid] = 0;
    const int e = expi[gid];
    sh_e[tid] = e;
    __syncthreads();
    atomicAdd(&sh_hist[e], 1);          // LDS histogram (order-independent)
    int r = 0;
    for (int j = 0; j < tid; ++j) r += (sh_e[j] == e) ? 1 : 0;
    rank[gid] = r;
    __syncthreads();
    if (tid < EE) blockHist[blockIdx.x * EE + tid] = sh_hist[tid];
}

// ---------------------------------------------------------------------------
// Kernel 2: single block, 64 threads (one per expert).
// chunkBase[b][e] = (# slots with expert < e overall) + (# slots with expert
// e in chunks < b). Also writes splits (as float, since d_out is f32).
// ---------------------------------------------------------------------------
__global__ void k_scan(const int* __restrict__ blockHist,
                       int* __restrict__ chunkBase,
                       float* __restrict__ splits_out) {
    __shared__ int total[EE];
    __shared__ int base[EE];
    const int e = threadIdx.x;   // 0..63
    int run = 0;
    for (int b = 0; b < NBLK; ++b) {
        chunkBase[b * EE + e] = run;
        run += blockHist[b * EE + e];
    }
    total[e] = run;
    __syncthreads();
    if (e == 0) {
        int acc = 0;
        for (int i = 0; i < EE; ++i) { base[i] = acc; acc += total[i]; }
    }
    __syncthreads();
    const int be = base[e];
    for (int b = 0; b < NBLK; ++b) chunkBase[b * EE + e] += be;
    splits_out[e] = (float)total[e];
}

// ---------------------------------------------------------------------------
// Kernel 3: dispatch copy. One block per flat slot; copies the 8 KB token row
// to its stable-sorted destination. 256 thr x 2 float4 = 2048 floats.
// ---------------------------------------------------------------------------
__global__ void k_dispatch(const float* __restrict__ x,
                           const int* __restrict__ expi,
                           const int* __restrict__ chunkBase,
                           const int* __restrict__ rank,
                           float* __restrict__ disp) {
    const int i = blockIdx.x;                       // flat slot
    const int e = expi[i];
    const int d = chunkBase[(i >> 8) * EE + e] + rank[i];
    const float4* __restrict__ src =
        (const float4*)(x + (size_t)(i / TOPK) * HH);
    float4* __restrict__ dst = (float4*)(disp + (size_t)d * HH);
    const int tid = threadIdx.x;
    dst[tid]       = src[tid];
    dst[tid + 256] = src[tid + 256];
}

// ---------------------------------------------------------------------------
// Kernel 4: combine. combined[t,:] = x[t,:] * sum_k w[t,k]
// (inverse permutation of the dispatch recovers x[t] exactly).
// ---------------------------------------------------------------------------
__global__ void k_combine(const float* __restrict__ x,
                          const float* __restrict__ w,
                          float* __restrict__ comb) {
    const int t = blockIdx.x;
    float sw = 0.f;
#pragma unroll
    for (int k = 0; k < TOPK; ++k) sw += w[t * TOPK + k];
    const float4* __restrict__ src = (const float4*)(x + (size_t)t * HH);
    float4* __restrict__ dst = (float4*)(comb + (size_t)t * HH);
    const int tid = threadIdx.x;
    float4 a = src[tid];
    a.x *= sw; a.y *= sw; a.z *= sw; a.w *= sw;
    dst[tid] = a;
    float4 b = src[tid + 256];
    b.x *= sw; b.y *= sw; b.z *= sw; b.w *= sw;
    dst[tid + 256] = b;
}

extern "C" void kernel_launch(void* const* d_in, const int* in_sizes, int n_in,
                              void* d_out, int out_size, void* d_ws, size_t ws_size,
                              hipStream_t stream) {
    const float* x    = (const float*)d_in[0];   // [T, H]
    const float* w    = (const float*)d_in[1];   // [T, TOPK]
    const int*   expi = (const int*)d_in[2];     // [T, TOPK]

    float* out    = (float*)d_out;
    float* disp   = out;                                  // [T*K, H]
    float* splits = out + (size_t)NFLAT * HH;             // [E]
    float* comb   = splits + EE;                          // [T, H]

    int* ws        = (int*)d_ws;
    int* blockHist = ws;                 // [NBLK][E]
    int* chunkBase = ws + NBLK * EE;     // [NBLK][E]
    int* rank      = ws + 2 * NBLK * EE; // [NFLAT]

    k_hist_rank<<<NBLK, 256, 0, stream>>>(expi, blockHist, rank);
    k_scan<<<1, EE, 0, stream>>>(blockHist, chunkBase, splits);
    k_dispatch<<<NFLAT, 256, 0, stream>>>(x, expi, chunkBase, rank, disp);
    k_combine<<<TT, 256, 0, stream>>>(x, w, comb);
}

// Round 3
// 211.904 us; speedup vs baseline: 1.2996x; 1.2996x over previous
//
#include <hip/hip_runtime.h>

// Problem constants (fixed by the reference)
#define TT    8192          // tokens
#define TOPK  8
#define HH    2048          // hidden
#define EE    64            // experts
#define NFLAT (TT * TOPK)   // 65536 flat (token, slot) pairs
#define NBLK  (NFLAT / 256) // 256 chunks of 256 slots
#define NSEG  16            // scan segments (NBLK / 16 chunks each)

typedef float f32x4 __attribute__((ext_vector_type(4)));

// ---------------------------------------------------------------------------
// Kernel 1: per-chunk expert histogram + stable in-chunk rank per slot.
// rank[i] = number of j < i within the chunk with the same expert.
// ---------------------------------------------------------------------------
__global__ void k_hist_rank(const int* __restrict__ expi,
                            int* __restrict__ blockHist,
                            int* __restrict__ rank) {
    __shared__ int sh_e[256];
    __shared__ int sh_hist[EE];
    const int tid = threadIdx.x;
    const int gid = blockIdx.x * 256 + tid;
    if (tid < EE) sh_hist[tid] = 0;
    const int e = expi[gid];
    sh_e[tid] = e;
    __syncthreads();
    atomicAdd(&sh_hist[e], 1);          // LDS histogram (order-independent)
    int r = 0;
    for (int j = 0; j < tid; ++j) r += (sh_e[j] == e) ? 1 : 0;
    rank[gid] = r;
    __syncthreads();
    if (tid < EE) blockHist[blockIdx.x * EE + tid] = sh_hist[tid];
}

// ---------------------------------------------------------------------------
// Kernel 2: parallel scan. One block, 1024 threads = 16 segments x 64 experts.
// chunkBase[b][e] = (# slots with expert < e) + (# slots expert e, chunk < b).
// Also emits splits (as float; d_out is f32).
// ---------------------------------------------------------------------------
__global__ void k_scan(const int* __restrict__ bh,
                       int* __restrict__ cb,
                       float* __restrict__ splits_out) {
    __shared__ int part[NSEG][EE];
    __shared__ int segbase[NSEG][EE];
    __shared__ int ebase[EE + 1];
    const int t = threadIdx.x;
    const int s = t >> 6;        // segment 0..15
    const int e = t & 63;        // expert
    int sum = 0;
#pragma unroll
    for (int b = 0; b < NBLK / NSEG; ++b)
        sum += bh[(s * (NBLK / NSEG) + b) * EE + e];
    part[s][e] = sum;
    __syncthreads();
    if (s == 0) {                // 64 threads: scan 16 segments per expert
        int acc = 0;
#pragma unroll
        for (int i = 0; i < NSEG; ++i) { segbase[i][e] = acc; acc += part[i][e]; }
        splits_out[e] = (float)acc;   // per-expert total
        ebase[e + 1] = acc;
    }
    __syncthreads();
    if (t == 0) {
        ebase[0] = 0;
        for (int i = 1; i <= EE; ++i) ebase[i] += ebase[i - 1];
    }
    __syncthreads();
    int run = ebase[e] + segbase[s][e];
#pragma unroll
    for (int b = 0; b < NBLK / NSEG; ++b) {
        const int idx = (s * (NBLK / NSEG) + b) * EE + e;
        cb[idx] = run;
        run += bh[idx];
    }
}

// ---------------------------------------------------------------------------
// Kernel 3: dispatch copy (+ fused combine on k==0 blocks).
// One block per flat slot; copies the 8 KB token row to its stable-sorted
// destination with NONTEMPORAL stores (write-once stream — keep x in L3).
// combined[t,:] = x[t,:] * sum_k w[t,k]  (inverse perm recovers x exactly).
// ---------------------------------------------------------------------------
__global__ void k_dispatch(const float* __restrict__ x,
                           const float* __restrict__ w,
                           const int* __restrict__ expi,
                           const int* __restrict__ chunkBase,
                           const int* __restrict__ rank,
                           float* __restrict__ disp,
                           float* __restrict__ comb) {
    const int i = blockIdx.x;                       // flat slot
    const int e = expi[i];
    const int d = chunkBase[(i >> 8) * EE + e] + rank[i];
    const int tok = i >> 3;                         // i / TOPK
    const f32x4* __restrict__ src = (const f32x4*)(x + (size_t)tok * HH);
    f32x4* __restrict__ dst = (f32x4*)(disp + (size_t)d * HH);
    const int tid = threadIdx.x;
    f32x4 a = src[tid];
    f32x4 b = src[tid + 256];
    __builtin_nontemporal_store(a, &dst[tid]);
    __builtin_nontemporal_store(b, &dst[tid + 256]);
    if ((i & 7) == 0) {                             // slot k==0: write combined
        float sw = 0.f;
#pragma unroll
        for (int k = 0; k < TOPK; ++k) sw += w[tok * TOPK + k];
        f32x4* __restrict__ cd = (f32x4*)(comb + (size_t)tok * HH);
        __builtin_nontemporal_store(a * sw, &cd[tid]);
        __builtin_nontemporal_store(b * sw, &cd[tid + 256]);
    }
}

extern "C" void kernel_launch(void* const* d_in, const int* in_sizes, int n_in,
                              void* d_out, int out_size, void* d_ws, size_t ws_size,
                              hipStream_t stream) {
    const float* x    = (const float*)d_in[0];   // [T, H]
    const float* w    = (const float*)d_in[1];   // [T, TOPK]
    const int*   expi = (const int*)d_in[2];     // [T, TOPK]

    float* out    = (float*)d_out;
    float* disp   = out;                                  // [T*K, H]
    float* splits = out + (size_t)NFLAT * HH;             // [E]
    float* comb   = splits + EE;                          // [T, H]

    int* ws        = (int*)d_ws;
    int* blockHist = ws;                 // [NBLK][E]
    int* chunkBase = ws + NBLK * EE;     // [NBLK][E]
    int* rank      = ws + 2 * NBLK * EE; // [NFLAT]

    k_hist_rank<<<NBLK, 256, 0, stream>>>(expi, blockHist, rank);
    k_scan<<<1, 1024, 0, stream>>>(blockHist, chunkBase, splits);
    k_dispatch<<<NFLAT, 256, 0, stream>>>(x, w, expi, chunkBase, rank, disp, comb);
}

// Round 4
// 129.557 us; speedup vs baseline: 2.1257x; 1.6356x over previous
//
#include <hip/hip_runtime.h>

// Problem constants (fixed by the reference)
#define TT    8192          // tokens
#define TOPK  8
#define HH    2048          // hidden
#define EE    64            // experts
#define NFLAT (TT * TOPK)   // 65536 flat (token, slot) pairs
#define NBLK  (NFLAT / 256) // 256 chunks of 256 slots
#define NSEG  16            // scan segments (NBLK / 16 chunks each)

typedef float f32x4 __attribute__((ext_vector_type(4)));

// ---------------------------------------------------------------------------
// Kernel 1: per-chunk expert histogram + stable in-chunk rank per slot.
// rank[i] = number of j < i within the chunk with the same expert.
// ---------------------------------------------------------------------------
__global__ void k_hist_rank(const int* __restrict__ expi,
                            int* __restrict__ blockHist,
                            int* __restrict__ rank) {
    __shared__ int sh_e[256];
    __shared__ int sh_hist[EE];
    const int tid = threadIdx.x;
    const int gid = blockIdx.x * 256 + tid;
    if (tid < EE) sh_hist[tid] = 0;
    const int e = expi[gid];
    sh_e[tid] = e;
    __syncthreads();
    atomicAdd(&sh_hist[e], 1);          // LDS histogram (order-independent)
    int r = 0;
    for (int j = 0; j < tid; ++j) r += (sh_e[j] == e) ? 1 : 0;
    rank[gid] = r;
    __syncthreads();
    if (tid < EE) blockHist[blockIdx.x * EE + tid] = sh_hist[tid];
}

// ---------------------------------------------------------------------------
// Kernel 2: parallel scan. One block, 1024 threads = 16 segments x 64 experts.
// chunkBase[b][e] = (# slots with expert < e) + (# slots expert e, chunk < b).
// Also emits splits (as float; d_out is f32).
// ---------------------------------------------------------------------------
__global__ void k_scan(const int* __restrict__ bh,
                       int* __restrict__ cb,
                       float* __restrict__ splits_out) {
    __shared__ int part[NSEG][EE];
    __shared__ int segbase[NSEG][EE];
    __shared__ int ebase[EE + 1];
    const int t = threadIdx.x;
    const int s = t >> 6;        // segment 0..15
    const int e = t & 63;        // expert
    int sum = 0;
#pragma unroll
    for (int b = 0; b < NBLK / NSEG; ++b)
        sum += bh[(s * (NBLK / NSEG) + b) * EE + e];
    part[s][e] = sum;
    __syncthreads();
    if (s == 0) {                // 64 threads: scan 16 segments per expert
        int acc = 0;
#pragma unroll
        for (int i = 0; i < NSEG; ++i) { segbase[i][e] = acc; acc += part[i][e]; }
        splits_out[e] = (float)acc;   // per-expert total
        ebase[e + 1] = acc;
    }
    __syncthreads();
    if (t == 0) {
        ebase[0] = 0;
        for (int i = 1; i <= EE; ++i) ebase[i] += ebase[i - 1];
    }
    __syncthreads();
    int run = ebase[e] + segbase[s][e];
#pragma unroll
    for (int b = 0; b < NBLK / NSEG; ++b) {
        const int idx = (s * (NBLK / NSEG) + b) * EE + e;
        cb[idx] = run;
        run += bh[idx];
    }
}

// ---------------------------------------------------------------------------
// Kernel 3: token-major dispatch + fused combine.
// One block per TOKEN: read the 8 KB row ONCE into registers, then write it
// to its 8 stable-sorted destinations + the weighted combined row.
// Read traffic = 64 MB compulsory, independent of cache behavior.
// All output streams are write-once -> nontemporal stores.
// ---------------------------------------------------------------------------
__global__ void k_dispatch_tok(const float* __restrict__ x,
                               const float* __restrict__ w,
                               const int* __restrict__ expi,
                               const int* __restrict__ chunkBase,
                               const int* __restrict__ rank,
                               float* __restrict__ disp,
                               float* __restrict__ comb) {
    const int tok = blockIdx.x;
    const int tid = threadIdx.x;
    __shared__ int sh_d[TOPK];
    if (tid < TOPK) {
        const int i = tok * TOPK + tid;
        const int e = expi[i];
        sh_d[tid] = chunkBase[(i >> 8) * EE + e] + rank[i];
    }
    float sw = 0.f;                       // block-uniform -> scalar loads
#pragma unroll
    for (int k = 0; k < TOPK; ++k) sw += w[tok * TOPK + k];
    const f32x4* __restrict__ src = (const f32x4*)(x + (size_t)tok * HH);
    const f32x4 a = src[tid];
    const f32x4 b = src[tid + 256];
    __syncthreads();
#pragma unroll
    for (int s = 0; s < TOPK; ++s) {
        f32x4* __restrict__ dst = (f32x4*)(disp + (size_t)sh_d[s] * HH);
        __builtin_nontemporal_store(a, &dst[tid]);
        __builtin_nontemporal_store(b, &dst[tid + 256]);
    }
    f32x4* __restrict__ cd = (f32x4*)(comb + (size_t)tok * HH);
    __builtin_nontemporal_store(a * sw, &cd[tid]);
    __builtin_nontemporal_store(b * sw, &cd[tid + 256]);
}

extern "C" void kernel_launch(void* const* d_in, const int* in_sizes, int n_in,
                              void* d_out, int out_size, void* d_ws, size_t ws_size,
                              hipStream_t stream) {
    const float* x    = (const float*)d_in[0];   // [T, H]
    const float* w    = (const float*)d_in[1];   // [T, TOPK]
    const int*   expi = (const int*)d_in[2];     // [T, TOPK]

    float* out    = (float*)d_out;
    float* disp   = out;                                  // [T*K, H]
    float* splits = out + (size_t)NFLAT * HH;             // [E]
    float* comb   = splits + EE;                          // [T, H]

    int* ws        = (int*)d_ws;
    int* blockHist = ws;                 // [NBLK][E]
    int* chunkBase = ws + NBLK * EE;     // [NBLK][E]
    int* rank      = ws + 2 * NBLK * EE; // [NFLAT]

    k_hist_rank<<<NBLK, 256, 0, stream>>>(expi, blockHist, rank);
    k_scan<<<1, 1024, 0, stream>>>(blockHist, chunkBase, splits);
    k_dispatch_tok<<<TT, 256, 0, stream>>>(x, w, expi, chunkBase, rank, disp, comb);
}